// Round 6
// baseline (7950.606 us; speedup 1.0000x reference)
//
#include <hip/hip_runtime.h>
#include <hip/hip_bf16.h>

// R6: one 1024-thread block per 16-sample group (8 blocks). All 512 Whh columns
// resident in the block's unified RF (wave w holds cols [w*32,w*32+32) as 128
// AGPR B-frags — same per-wave footprint as R5, 4 waves/SIMD x <=512 regs fits).
// h exchange is intra-block: double-buffered frag-major LDS + one barrier/step.
// No cross-block sync at all. GEMMs unchanged from R5.

typedef __attribute__((ext_vector_type(8))) short bf16x8;
typedef __attribute__((ext_vector_type(4))) float f32x4;

#define T_STEPS 512
#define NBATCH  128
#define HID     512
#define INSZ    256
#define HB      8192   // shorts per LDS h buffer (16 samples x 512 cols, frag-major)

static __device__ __forceinline__ float bf2f(__hip_bfloat16 v) { return __bfloat162float(v); }
static __device__ __forceinline__ __hip_bfloat16 f2bf(float v) { return __float2bfloat16(v); }

union BF8 { bf16x8 v; unsigned short u[8]; };
static __device__ __forceinline__ unsigned short f2bfbits(float x) {
    __hip_bfloat16 b = __float2bfloat16(x);
    return *reinterpret_cast<unsigned short*>(&b);
}
static __device__ __forceinline__ float loadE(const void* p, size_t i, bool f32) {
    return f32 ? ((const float*)p)[i] : bf2f(((const __hip_bfloat16*)p)[i]);
}
// tanh(x) = 1 - 2/(e^{2x}+1); exp over/underflow saturates correctly to +-1.
static __device__ __forceinline__ float fast_tanh(float x) {
    float e = __expf(2.f * x);
    float r = __builtin_amdgcn_rcpf(e + 1.f);
    return 1.f - 2.f * r;
}

// ---------------- dtype probe: even uint16s of fp32 data are random mantissa halves
__global__ void detect_dtype(const unsigned short* __restrict__ x, unsigned int* __restrict__ dflag) {
    if (threadIdx.x == 0 && blockIdx.x == 0) {
        int sane = 0;
        for (int i = 0; i < 64; ++i) {
            unsigned short v = x[2 * i];
            unsigned int e = (v >> 7) & 0xFF;
            if (v == 0 || (e >= 0x60 && e <= 0x9F)) ++sane;
        }
        *dflag = (sane >= 48) ? 0u : 1u;  // 0 = bf16 data, 1 = fp32 data
    }
}

// ---------------- GEMM: out[M][N] = A[M][K] @ W[N][K]^T + b1[N] (+ b2[N])
__global__ __launch_bounds__(256, 4) void gemm_bt64(
    const void* __restrict__ A, const void* __restrict__ W,
    const void* __restrict__ b1, const void* __restrict__ b2,
    void* __restrict__ out, int M, int N, int K,
    const int* __restrict__ lengths, const unsigned int* __restrict__ dflag,
    int aIsOrig, int outIsOutput)
{
    const int r0 = blockIdx.y * 64;
    if (lengths) {  // rows are (t*128+n); a 64-row tile is one t, n0 in {0,64}; sorted desc.
        int t = r0 >> 7, n0 = r0 & 127;
        if (lengths[n0] <= t) return;
    }
    const bool f32 = *dflag != 0;
    const int c0 = blockIdx.x * 64;
    __shared__ short As[64 * 32];
    __shared__ short Bs[64 * 32];
    const int tid = threadIdx.x;
    const int lane = tid & 63, wave = tid >> 6;
    const int lrow = tid >> 2, lk = (tid & 3) * 8;
    const int q = (lane >> 4) & 3, l15 = lane & 15;

    f32x4 z = {0.f, 0.f, 0.f, 0.f};
    f32x4 acc[4];
#pragma unroll
    for (int m = 0; m < 4; ++m) acc[m] = z;

    for (int kk = 0; kk < K; kk += 32) {
        if (aIsOrig && f32) {
            const float* f = (const float*)A + (size_t)(r0 + lrow) * K + kk + lk;
            BF8 u;
#pragma unroll
            for (int i = 0; i < 8; ++i) u.u[i] = f2bfbits(f[i]);
            *(bf16x8*)&As[lrow * 32 + lk] = u.v;
        } else {
            *(bf16x8*)&As[lrow * 32 + lk] =
                *(const bf16x8*)((const __hip_bfloat16*)A + (size_t)(r0 + lrow) * K + kk + lk);
        }
        if (f32) {
            const float* f = (const float*)W + (size_t)(c0 + lrow) * K + kk + lk;
            BF8 u;
#pragma unroll
            for (int i = 0; i < 8; ++i) u.u[i] = f2bfbits(f[i]);
            *(bf16x8*)&Bs[lrow * 32 + lk] = u.v;
        } else {
            *(bf16x8*)&Bs[lrow * 32 + lk] =
                *(const bf16x8*)((const __hip_bfloat16*)W + (size_t)(c0 + lrow) * K + kk + lk);
        }
        __syncthreads();
        bf16x8 bfrag = *(const bf16x8*)&Bs[(wave * 16 + l15) * 32 + q * 8];
#pragma unroll
        for (int m = 0; m < 4; ++m) {
            bf16x8 afrag = *(const bf16x8*)&As[(m * 16 + l15) * 32 + q * 8];
            acc[m] = __builtin_amdgcn_mfma_f32_16x16x32_bf16(afrag, bfrag, acc[m], 0, 0, 0);
        }
        __syncthreads();
    }
    const int col = c0 + wave * 16 + l15;
    float bias = loadE(b1, col, f32) + (b2 ? loadE(b2, col, f32) : 0.f);
#pragma unroll
    for (int m = 0; m < 4; ++m) {
#pragma unroll
        for (int r = 0; r < 4; ++r) {
            int row = r0 + m * 16 + q * 4 + r;
            float v = acc[m][r] + bias;
            if (outIsOutput && f32) ((float*)out)[(size_t)row * N + col] = v;
            else ((__hip_bfloat16*)out)[(size_t)row * N + col] = f2bf(v);
        }
    }
}

// ---------------- recurrence: 8 blocks (one per 16-sample group), 1024 threads.
// Wave w owns output cols [w*32, w*32+32); full Whh resident across block's RF.
// LDS h layout FRAG-MAJOR: (sample s, col j) at ((j>>3)*16+s)*8 + (j&7); the
// A-frag for (c,q,l15) is one b128 at ((c*4+q)*16+l15)*8 (16B lane stride).
__global__ __launch_bounds__(1024, 1) void rnn_recur(
    const __hip_bfloat16* __restrict__ xp,    // [T*128][512] bf16 (ws)
    const void* __restrict__ Whh,             // [512][512] orig dtype
    const void* __restrict__ h0all,           // [2][128][512] orig dtype
    int layer,
    const int* __restrict__ lengths,          // [128] sorted desc
    __hip_bfloat16* __restrict__ out0,        // [T*128][512] bf16 or nullptr
    void* __restrict__ hout,                  // d_out base; final h at elem houtOff
    int houtOff,
    __hip_bfloat16* __restrict__ hfbf,        // [128][512] final h bf16 (logits input)
    const unsigned int* __restrict__ dflag)
{
    const int gb = blockIdx.x;
    const int s0 = gb * 16;
    const int tid = threadIdx.x, lane = tid & 63, wave = tid >> 6;
    const int q = (lane >> 4) & 3, l15 = lane & 15;
    const int colBase = wave * 32;            // this wave's 32 output columns
    const bool f32 = *dflag != 0;
    const size_t h0base = (size_t)layer * NBATCH * HID;
    __shared__ short hlds[2 * HB];            // 32 KB

    // persistent B fragments: Whh[j][k], j in wave's 32 cols, full K (128 regs)
    bf16x8 bfr[2][16];
    if (f32) {
#pragma unroll
        for (int tau = 0; tau < 2; ++tau)
#pragma unroll
            for (int c = 0; c < 16; ++c) {
                const float* f = (const float*)Whh + (size_t)(colBase + tau * 16 + l15) * HID + c * 32 + q * 8;
                BF8 u;
#pragma unroll
                for (int i = 0; i < 8; ++i) u.u[i] = f2bfbits(f[i]);
                bfr[tau][c] = u.v;
            }
    } else {
#pragma unroll
        for (int tau = 0; tau < 2; ++tau)
#pragma unroll
            for (int c = 0; c < 16; ++c)
                bfr[tau][c] = *(const bf16x8*)((const __hip_bfloat16*)Whh +
                    (size_t)(colBase + tau * 16 + l15) * HID + c * 32 + q * 8);
    }

    int len_r[4];
#pragma unroll
    for (int r = 0; r < 4; ++r) len_r[r] = lengths[s0 + q * 4 + r];

    float cur[2][4];  // owned h: sample q*4+r, col colBase + tau*16 + l15
#pragma unroll
    for (int tau = 0; tau < 2; ++tau)
#pragma unroll
        for (int r = 0; r < 4; ++r)
            cur[tau][r] = loadE(h0all, h0base + (size_t)(s0 + q * 4 + r) * HID + colBase + tau * 16 + l15, f32);

    // stage S_0 into LDS buf 0 (frag-major): thread covers sample sr, cols cb8..cb8+7
    {
        const int sr = tid >> 6, cb8 = (tid & 63) * 8;
        BF8 u0;
#pragma unroll
        for (int i = 0; i < 8; ++i)
            u0.u[i] = f2bfbits(loadE(h0all, h0base + (size_t)(s0 + sr) * HID + cb8 + i, f32));
        *(bf16x8*)&hlds[(((cb8 >> 3) * 16) + sr) * 8] = u0.v;
    }
    __syncthreads();

    const int Tg = lengths[s0];   // group max length (sorted desc)

    // preload xp for t=0
    float xv[2][4];
    {
        const __hip_bfloat16* xprow = xp + (size_t)s0 * HID;
#pragma unroll
        for (int tau = 0; tau < 2; ++tau)
#pragma unroll
            for (int r = 0; r < 4; ++r)
                xv[tau][r] = bf2f(xprow[(size_t)(q * 4 + r) * HID + colBase + tau * 16 + l15]);
    }

    for (int t = 0; t < Tg; ++t) {
        const int cb_ = t & 1, nb = (t + 1) & 1;
        const short* hrd = &hlds[cb_ * HB];
        short* hwr = &hlds[nb * HB];

        // prefetch next step's xp (overlaps MFMA)
        float xn[2][4];
        if (t + 1 < Tg) {
            const __hip_bfloat16* xprow = xp + ((size_t)(t + 1) * NBATCH + s0) * HID;
#pragma unroll
            for (int tau = 0; tau < 2; ++tau)
#pragma unroll
                for (int r = 0; r < 4; ++r)
                    xn[tau][r] = bf2f(xprow[(size_t)(q * 4 + r) * HID + colBase + tau * 16 + l15]);
        }

        f32x4 zz = {0.f, 0.f, 0.f, 0.f};
        f32x4 acc[2] = {zz, zz};
#pragma unroll
        for (int c = 0; c < 16; ++c) {
            bf16x8 a = *(const bf16x8*)&hrd[((c * 4 + q) * 16 + l15) * 8];
            acc[0] = __builtin_amdgcn_mfma_f32_16x16x32_bf16(a, bfr[0][c], acc[0], 0, 0, 0);
            acc[1] = __builtin_amdgcn_mfma_f32_16x16x32_bf16(a, bfr[1][c], acc[1], 0, 0, 0);
        }

        // h_{t+1}: tanh, write own cols to next LDS buf (+ out0 global)
#pragma unroll
        for (int tau = 0; tau < 2; ++tau)
#pragma unroll
            for (int r = 0; r < 4; ++r) {
                const int sl = q * 4 + r;
                const int j = colBase + tau * 16 + l15;
                float hnew = fast_tanh(acc[tau][r] + xv[tau][r]);
                float val = (t < len_r[r]) ? hnew : cur[tau][r];
                cur[tau][r] = val;
                unsigned short bits = f2bfbits(val);
                hwr[((j >> 3) * 16 + sl) * 8 + (j & 7)] = (short)bits;
                if (out0 && t < len_r[r])
                    out0[((size_t)t * NBATCH + s0 + sl) * HID + j] =
                        *reinterpret_cast<__hip_bfloat16*>(&bits);
            }
        __syncthreads();
#pragma unroll
        for (int tau = 0; tau < 2; ++tau)
#pragma unroll
            for (int r = 0; r < 4; ++r) xv[tau][r] = xn[tau][r];
    }

    // finals: h to d_out (output dtype) + bf16 copy for logits GEMM
#pragma unroll
    for (int tau = 0; tau < 2; ++tau)
#pragma unroll
        for (int r = 0; r < 4; ++r) {
            size_t idx = (size_t)(s0 + q * 4 + r) * HID + colBase + tau * 16 + l15;
            if (f32) ((float*)hout)[houtOff + idx] = cur[tau][r];
            else     ((__hip_bfloat16*)hout)[houtOff + idx] = f2bf(cur[tau][r]);
            hfbf[idx] = f2bf(cur[tau][r]);
        }
}

extern "C" void kernel_launch(void* const* d_in, const int* in_sizes, int n_in,
                              void* d_out, int out_size, void* d_ws, size_t ws_size,
                              hipStream_t stream) {
    const void* x    = d_in[0];
    const void* h0   = d_in[1];
    const int*  lens = (const int*)d_in[2];
    const void* Wih0 = d_in[3];
    const void* bih0 = d_in[4];
    const void* Whh0 = d_in[5];
    const void* bhh0 = d_in[6];
    const void* Wih1 = d_in[7];
    const void* bih1 = d_in[8];
    const void* Whh1 = d_in[9];
    const void* bhh1 = d_in[10];
    const void* Wfc  = d_in[11];
    const void* bfc  = d_in[12];

    const size_t MROWS = (size_t)T_STEPS * NBATCH;          // 65536
    size_t off = 0;
    auto take = [&](size_t bytes) { size_t o = off; off += (bytes + 255) & ~255ull; return o; };
    const size_t off_xp   = take(MROWS * HID * 2);          // 64 MB bf16
    const size_t off_out0 = take(MROWS * HID * 2);          // 64 MB bf16
    const size_t off_hfbf = take(2ull * NBATCH * HID * 2);
    const size_t off_dfl  = take(256);
    if (ws_size < off) return;  // workspace too small

    char* ws = (char*)d_ws;
    __hip_bfloat16* xp    = (__hip_bfloat16*)(ws + off_xp);
    __hip_bfloat16* out0  = (__hip_bfloat16*)(ws + off_out0);
    __hip_bfloat16* hfbf  = (__hip_bfloat16*)(ws + off_hfbf);
    unsigned int*   dflag = (unsigned int*)(ws + off_dfl);

    detect_dtype<<<1, 64, 0, stream>>>((const unsigned short*)x, dflag);

    // layer 0 input GEMM: xp0 = x @ Wih0^T + bih0 + bhh0
    gemm_bt64<<<dim3(HID / 64, MROWS / 64), 256, 0, stream>>>(
        x, Wih0, bih0, bhh0, xp, (int)MROWS, HID, INSZ, lens, dflag, 1, 0);
    // layer 0 recurrence (writes out0 + final h into d_out at elem 16384)
    rnn_recur<<<8, 1024, 0, stream>>>(
        xp, Whh0, h0, 0, lens, out0, d_out, NBATCH * 128, hfbf, dflag);
    // layer 1 input GEMM: xp1 = out0 @ Wih1^T + bih1 + bhh1 (reuse xp region)
    gemm_bt64<<<dim3(HID / 64, MROWS / 64), 256, 0, stream>>>(
        out0, Wih1, bih1, bhh1, xp, (int)MROWS, HID, HID, lens, dflag, 0, 0);
    // layer 1 recurrence (final h into d_out at elem 16384 + 65536)
    rnn_recur<<<8, 1024, 0, stream>>>(
        xp, Whh1, h0, 1, lens, nullptr, d_out,
        NBATCH * 128 + NBATCH * HID, hfbf + (size_t)NBATCH * HID, dflag);
    // logits = h1_final @ Wfc^T + bfc
    gemm_bt64<<<dim3(2, 2), 256, 0, stream>>>(
        hfbf + (size_t)NBATCH * HID, Wfc, bfc, nullptr,
        d_out, NBATCH, 128, HID, nullptr, dflag, 0, 1);
}